// Round 1
// baseline (1069.099 us; speedup 1.0000x reference)
//
#include <hip/hip_runtime.h>

// out[e] = edge_attr[e] / segsum(edge_attr, row)[col[e]]
// Pass A: zero rowsum (ws).  Pass B: atomic scatter-add rowsum[row[e]] += attr[e].
// Pass C: rowsum[i] = 1/rowsum[i].  Pass D: out[e] = rowsum[col[e]] * attr[e].

__global__ void zero_ws_kernel(float* __restrict__ ws, const int* __restrict__ Np) {
    const int N = *Np;  // int32 view is correct for i32 or LE i64 (value < 2^31)
    const int stride = gridDim.x * blockDim.x;
    for (int i = blockIdx.x * blockDim.x + threadIdx.x; i < N; i += stride)
        ws[i] = 0.0f;
}

__global__ void rowsum_atomic_kernel(const int* __restrict__ row,
                                     const float* __restrict__ attr,
                                     float* __restrict__ rowsum, int E) {
    const int tid = blockIdx.x * blockDim.x + threadIdx.x;
    const int stride = gridDim.x * blockDim.x;
    const int E4 = E >> 2;
    for (int i = tid; i < E4; i += stride) {
        const int4   r = reinterpret_cast<const int4*>(row)[i];
        const float4 a = reinterpret_cast<const float4*>(attr)[i];
        atomicAdd(&rowsum[r.x], a.x);
        atomicAdd(&rowsum[r.y], a.y);
        atomicAdd(&rowsum[r.z], a.z);
        atomicAdd(&rowsum[r.w], a.w);
    }
    for (int i = (E4 << 2) + tid; i < E; i += stride)
        atomicAdd(&rowsum[row[i]], attr[i]);
}

__global__ void recip_kernel(float* __restrict__ rowsum, const int* __restrict__ Np) {
    const int N = *Np;
    const int stride = gridDim.x * blockDim.x;
    for (int i = blockIdx.x * blockDim.x + threadIdx.x; i < N; i += stride)
        rowsum[i] = 1.0f / rowsum[i];
}

__global__ void gather_scale_kernel(const int* __restrict__ col,
                                    const float* __restrict__ attr,
                                    const float* __restrict__ rnorm,
                                    float* __restrict__ out, int E) {
    const int tid = blockIdx.x * blockDim.x + threadIdx.x;
    const int stride = gridDim.x * blockDim.x;
    const int E4 = E >> 2;
    for (int i = tid; i < E4; i += stride) {
        const int4   c = reinterpret_cast<const int4*>(col)[i];
        const float4 a = reinterpret_cast<const float4*>(attr)[i];
        float4 o;
        o.x = rnorm[c.x] * a.x;
        o.y = rnorm[c.y] * a.y;
        o.z = rnorm[c.z] * a.z;
        o.w = rnorm[c.w] * a.w;
        reinterpret_cast<float4*>(out)[i] = o;
    }
    for (int i = (E4 << 2) + tid; i < E; i += stride)
        out[i] = rnorm[col[i]] * attr[i];
}

extern "C" void kernel_launch(void* const* d_in, const int* in_sizes, int n_in,
                              void* d_out, int out_size, void* d_ws, size_t ws_size,
                              hipStream_t stream) {
    const int*   edge_index = (const int*)d_in[0];     // [2, E] row-major
    const float* edge_attr  = (const float*)d_in[1];   // [E]
    const int*   Np         = (const int*)d_in[2];     // scalar N on device

    const int E = in_sizes[1];
    const int* row = edge_index;
    const int* col = edge_index + E;
    float* rowsum = (float*)d_ws;                      // N floats (N ~1e6 << ws)
    float* out    = (float*)d_out;

    const dim3 block(256);
    const dim3 gridN(2048);                            // grid-stride covers any N
    const int workE = (E + 3) >> 2;
    int gE = (workE + 255) / 256;
    if (gE > 2048) gE = 2048;
    const dim3 gridE(gE);

    zero_ws_kernel      <<<gridN, block, 0, stream>>>(rowsum, Np);
    rowsum_atomic_kernel<<<gridE, block, 0, stream>>>(row, edge_attr, rowsum, E);
    recip_kernel        <<<gridN, block, 0, stream>>>(rowsum, Np);
    gather_scale_kernel <<<gridE, block, 0, stream>>>(col, edge_attr, rowsum, out, E);
}

// Round 2
// 375.339 us; speedup vs baseline: 2.8484x; 2.8484x over previous
//
#include <hip/hip_runtime.h>
#include <stdint.h>

// out[e] = edge_attr[e] / segsum(edge_attr, row)[col[e]]
//
// Fast path (needs ~181 MB ws): bucketed two-phase reduction to avoid
// 20M device-scope f32 atomics (round 1 showed each atomic write-throughs
// ~30B to the memory side; 925us of 1069us total).
//   P0: zero per-bucket tail counters.
//   P1: per-4096-edge tile block counting sort by bucket (row>>12), one
//       global atomic per (tile,bucket), coalesced pair flush.
//   P2: one block per bucket: stream pairs, LDS f32-atomic bins, store 1/sum.
//   P3: out[e] = rnorm[col[e]] * attr[e]  (vectorized gather/scale).
// Fallback path (small ws): round-0 global-atomic version.

#define BKT_BITS   12
#define BKT_W      (1 << BKT_BITS)          // 4096 nodes per bucket
#define NB         256                       // max buckets -> supports N <= 1,048,576
#define NMAX       (NB << BKT_BITS)
#define TILE       4096
#define BLOCK1     256
#define TAILPAD    8                         // pad tails 32B apart (atomic channel spread)

using ull = unsigned long long;

// ---------------- fast path ----------------

__global__ void zero_tails_kernel(int* __restrict__ tails) {
    tails[blockIdx.x * blockDim.x + threadIdx.x] = 0;
}

__global__ __launch_bounds__(BLOCK1) void scatter_kernel(
    const int* __restrict__ row, const float* __restrict__ attr,
    ull* __restrict__ pairsG, int* __restrict__ tails, int E, int C)
{
    __shared__ int hist[NB];
    __shared__ int scanb[NB];
    __shared__ int gbase[NB];
    __shared__ ull pairs[TILE];

    const int t = threadIdx.x;
    const int nTiles = (E + TILE - 1) / TILE;

    for (int tile = blockIdx.x; tile < nTiles; tile += gridDim.x) {
        const long base = (long)tile * TILE;
        hist[t] = 0;
        __syncthreads();

        int r[16]; float a[16]; int rk[16]; int bk[16];
        #pragma unroll
        for (int k = 0; k < 4; ++k) {
            const long e0 = base + (long)k * (BLOCK1 * 4) + t * 4;
            if (e0 + 3 < (long)E) {
                const int4   rv = *reinterpret_cast<const int4*>(row + e0);
                const float4 av = *reinterpret_cast<const float4*>(attr + e0);
                r[k*4+0]=rv.x; r[k*4+1]=rv.y; r[k*4+2]=rv.z; r[k*4+3]=rv.w;
                a[k*4+0]=av.x; a[k*4+1]=av.y; a[k*4+2]=av.z; a[k*4+3]=av.w;
                #pragma unroll
                for (int j = 0; j < 4; ++j) bk[k*4+j] = r[k*4+j] >> BKT_BITS;
            } else {
                #pragma unroll
                for (int j = 0; j < 4; ++j) {
                    const long e = e0 + j;
                    if (e < (long)E) {
                        r[k*4+j] = row[e]; a[k*4+j] = attr[e];
                        bk[k*4+j] = r[k*4+j] >> BKT_BITS;
                    } else {
                        bk[k*4+j] = -1;
                    }
                }
            }
        }
        #pragma unroll
        for (int i = 0; i < 16; ++i)
            if (bk[i] >= 0) rk[i] = atomicAdd(&hist[bk[i]], 1);
        __syncthreads();

        const int cnt = hist[t];
        scanb[t] = cnt;
        __syncthreads();
        for (int off = 1; off < NB; off <<= 1) {       // Hillis-Steele inclusive scan
            const int v = (t >= off) ? scanb[t - off] : 0;
            __syncthreads();
            scanb[t] += v;
            __syncthreads();
        }
        scanb[t] -= cnt;                               // exclusive base (own slot only)
        if (cnt > 0) gbase[t] = atomicAdd(&tails[t * TAILPAD], cnt);
        __syncthreads();

        #pragma unroll
        for (int i = 0; i < 16; ++i) {
            if (bk[i] >= 0) {
                const int s = scanb[bk[i]] + rk[i];
                pairs[s] = ((ull)__float_as_uint(a[i]) << 32) | (unsigned)r[i];
            }
        }
        __syncthreads();

        const long rem = (long)E - base;
        const int total = rem < TILE ? (int)rem : TILE;
        for (int s = t; s < total; s += BLOCK1) {
            const ull p  = pairs[s];
            const unsigned rr = (unsigned)p;
            const int bb = (int)(rr >> BKT_BITS);
            const long dst = (long)gbase[bb] + (s - scanb[bb]);
            if (dst < (long)C)
                pairsG[(size_t)bb * (size_t)C + (size_t)dst] = p;
        }
        __syncthreads();
    }
}

#define BLOCK2 1024
__global__ __launch_bounds__(BLOCK2) void bucket_reduce_kernel(
    const ull* __restrict__ pairsG, const int* __restrict__ tails,
    float* __restrict__ rnorm, const int* __restrict__ Np, int C)
{
    __shared__ float bins[BKT_W];                      // 16 KB
    const int N  = *Np;
    const int nB = (N + BKT_W - 1) >> BKT_BITS;
    for (int b = blockIdx.x; b < nB; b += gridDim.x) {
        for (int i = threadIdx.x; i < BKT_W; i += BLOCK2) bins[i] = 0.0f;
        __syncthreads();
        int cnt = tails[b * TAILPAD];
        if (cnt > C) cnt = C;
        const ull* src = pairsG + (size_t)b * (size_t)C;
        const int cnt2 = cnt & ~1;
        for (int i = threadIdx.x * 2; i < cnt2; i += BLOCK2 * 2) {
            const uint4 pp = *reinterpret_cast<const uint4*>(src + i);  // 2 pairs
            atomicAdd(&bins[pp.x & (BKT_W - 1)], __uint_as_float(pp.y));
            atomicAdd(&bins[pp.z & (BKT_W - 1)], __uint_as_float(pp.w));
        }
        if ((cnt & 1) && threadIdx.x == 0) {
            const ull p = src[cnt - 1];
            atomicAdd(&bins[(unsigned)p & (BKT_W - 1)],
                      __uint_as_float((unsigned)(p >> 32)));
        }
        __syncthreads();
        const int lo = b << BKT_BITS;
        int hi = N - lo; if (hi > BKT_W) hi = BKT_W;
        for (int i = threadIdx.x; i < hi; i += BLOCK2)
            rnorm[lo + i] = 1.0f / bins[i];
        __syncthreads();
    }
}

// ---------------- shared gather pass ----------------

__global__ void gather_scale_kernel(const int* __restrict__ col,
                                    const float* __restrict__ attr,
                                    const float* __restrict__ rnorm,
                                    float* __restrict__ out, int E) {
    const int tid = blockIdx.x * blockDim.x + threadIdx.x;
    const int stride = gridDim.x * blockDim.x;
    const int E4 = E >> 2;
    for (int i = tid; i < E4; i += stride) {
        const int4   c = reinterpret_cast<const int4*>(col)[i];
        const float4 a = reinterpret_cast<const float4*>(attr)[i];
        float4 o;
        o.x = rnorm[c.x] * a.x;
        o.y = rnorm[c.y] * a.y;
        o.z = rnorm[c.z] * a.z;
        o.w = rnorm[c.w] * a.w;
        reinterpret_cast<float4*>(out)[i] = o;
    }
    for (int i = (E4 << 2) + tid; i < E; i += stride)
        out[i] = rnorm[col[i]] * attr[i];
}

// ---------------- fallback path (round-0 atomic version) ----------------

__global__ void zero_ws_kernel(float* __restrict__ ws, const int* __restrict__ Np) {
    const int N = *Np;
    const int stride = gridDim.x * blockDim.x;
    for (int i = blockIdx.x * blockDim.x + threadIdx.x; i < N; i += stride)
        ws[i] = 0.0f;
}

__global__ void rowsum_atomic_kernel(const int* __restrict__ row,
                                     const float* __restrict__ attr,
                                     float* __restrict__ rowsum, int E) {
    const int tid = blockIdx.x * blockDim.x + threadIdx.x;
    const int stride = gridDim.x * blockDim.x;
    const int E4 = E >> 2;
    for (int i = tid; i < E4; i += stride) {
        const int4   r = reinterpret_cast<const int4*>(row)[i];
        const float4 a = reinterpret_cast<const float4*>(attr)[i];
        atomicAdd(&rowsum[r.x], a.x);
        atomicAdd(&rowsum[r.y], a.y);
        atomicAdd(&rowsum[r.z], a.z);
        atomicAdd(&rowsum[r.w], a.w);
    }
    for (int i = (E4 << 2) + tid; i < E; i += stride)
        atomicAdd(&rowsum[row[i]], attr[i]);
}

__global__ void recip_kernel(float* __restrict__ rowsum, const int* __restrict__ Np) {
    const int N = *Np;
    const int stride = gridDim.x * blockDim.x;
    for (int i = blockIdx.x * blockDim.x + threadIdx.x; i < N; i += stride)
        rowsum[i] = 1.0f / rowsum[i];
}

// ---------------- launch ----------------

extern "C" void kernel_launch(void* const* d_in, const int* in_sizes, int n_in,
                              void* d_out, int out_size, void* d_ws, size_t ws_size,
                              hipStream_t stream) {
    const int*   edge_index = (const int*)d_in[0];     // [2, E]
    const float* edge_attr  = (const float*)d_in[1];   // [E]
    const int*   Np         = (const int*)d_in[2];     // scalar N (device)

    const int E = in_sizes[1];
    const int* row = edge_index;
    const int* col = edge_index + E;
    float* out = (float*)d_out;

    const dim3 block(256);
    const int workE = (E + 3) >> 2;
    int gE = (workE + 255) / 256;
    if (gE > 2048) gE = 2048;
    const dim3 gridE(gE);

    int C = E / NB + 8192;                 // per-bucket capacity, >>28 sigma margin
    C = (C + 1) & ~1;                      // even -> 16B-aligned pair loads
    const size_t tailsBytes = (size_t)NB * TAILPAD * sizeof(int);   // 8 KB
    const size_t rnormBytes = (size_t)NMAX * sizeof(float);         // 4 MB
    const size_t pairsBytes = (size_t)NB * (size_t)C * sizeof(ull);
    const size_t need = tailsBytes + rnormBytes + pairsBytes;

    if (ws_size >= need) {
        int*   tails = (int*)d_ws;
        float* rnorm = (float*)((char*)d_ws + tailsBytes);
        ull*   pairs = (ull*)((char*)d_ws + tailsBytes + rnormBytes);

        const int nTiles = (E + TILE - 1) / TILE;
        zero_tails_kernel   <<<(NB * TAILPAD) / 256, 256, 0, stream>>>(tails);
        scatter_kernel      <<<nTiles, BLOCK1, 0, stream>>>(row, edge_attr, pairs, tails, E, C);
        bucket_reduce_kernel<<<NB, BLOCK2, 0, stream>>>(pairs, tails, rnorm, Np, C);
        gather_scale_kernel <<<gridE, block, 0, stream>>>(col, edge_attr, rnorm, out, E);
    } else {
        float* rowsum = (float*)d_ws;
        const dim3 gridN(2048);
        zero_ws_kernel      <<<gridN, block, 0, stream>>>(rowsum, Np);
        rowsum_atomic_kernel<<<gridE, block, 0, stream>>>(row, edge_attr, rowsum, E);
        recip_kernel        <<<gridN, block, 0, stream>>>(rowsum, Np);
        gather_scale_kernel <<<gridE, block, 0, stream>>>(col, edge_attr, rowsum, out, E);
    }
}